// Round 4
// baseline (150.113 us; speedup 1.0000x reference)
//
#include <hip/hip_runtime.h>

// LocalConnectivity: diamond (L1-ball radius 5) circular convolution over
// (B=64, H=512, W=512) fp32, weight per L1-distance d: w_d = d_in[1][d-1].
//
// Decomposition (exact):
//   h_a[r][j] = sum_{|b| <= 5-a} w_{a+|b|} * s[r][(j+b)&511]   (h_0 excludes b=0)
//   out[i][j] = h_0[i][j] + sum_{a=1..5} (h_a[i-a][j] + h_a[i+a][j])
//
// Ladder: R1 spills (launch_bounds VGPR cap) 217us -> R2 direct-global 67us
// (latency-bound, 130 loads/thread) -> R3 LDS row-ring 42us (pipes serialized:
// VALU 22%, LDS 30%, HBM 36%; barrier + ds_read latency chain).
// R4: ONE WAVE (64 lanes) owns the whole 512-col row, 8 cols/lane. The +-5
// column halo comes from lanes t+-1 via __shfl (10 shuffles/row) -- zero LDS,
// zero barriers, W-wrap = natural lane rotation. Global prefetch ring 4 rows
// deep (row rr+3 issued at iter rr, ~2 iters ~1300 cyc ahead of use). First
// vertical contribution (a=5, at iter rr == output row) is an assignment ->
// no acc zero-init/reset.

#define LC_H 512
#define LC_W 512
#define LC_TY 16
#define LC_NR (LC_TY + 10)  // 26 source rows per strip

__global__ __launch_bounds__(64)
void LocalConnectivity_kernel(const float* __restrict__ in,
                              const float* __restrict__ wp,
                              float* __restrict__ out) {
    const int t = threadIdx.x;            // lane 0..63, owns cols 8t..8t+7
    const int b = blockIdx.y;             // batch
    const int r0 = blockIdx.x * LC_TY;    // first output row of strip

    const float w1 = wp[0], w2 = wp[1], w3 = wp[2], w4 = wp[3], w5 = wp[4];

    const float* __restrict__ src = in + (size_t)b * LC_H * LC_W;
    float* __restrict__ dst = out + (size_t)b * LC_H * LC_W;

    const int laneL = (t + 63) & 63;      // left neighbor (wraps W)
    const int laneR = (t + 1) & 63;       // right neighbor (wraps W)

    float ring[4][8];                     // prefetch ring: row j in slot j%4
    float acc[11][8];                     // output-row accumulator ring

#pragma unroll
    for (int j = 0; j < 3; ++j) {         // prologue: rows 0..2 -> slots 0..2
        const float* rp = src + ((r0 + j - 5) & (LC_H - 1)) * LC_W + t * 8;
        const float4 f0 = *reinterpret_cast<const float4*>(rp);
        const float4 f1 = *reinterpret_cast<const float4*>(rp + 4);
        ring[j][0] = f0.x; ring[j][1] = f0.y; ring[j][2] = f0.z; ring[j][3] = f0.w;
        ring[j][4] = f1.x; ring[j][5] = f1.y; ring[j][6] = f1.z; ring[j][7] = f1.w;
    }

#pragma unroll
    for (int rr = 0; rr < LC_NR; ++rr) {
        // issue prefetch of row rr+3 first (used at iter rr+3)
        if (rr + 3 < LC_NR) {
            const int s = (rr + 3) % 4;
            const float* rp = src + ((r0 + rr - 2) & (LC_H - 1)) * LC_W + t * 8;
            const float4 f0 = *reinterpret_cast<const float4*>(rp);
            const float4 f1 = *reinterpret_cast<const float4*>(rp + 4);
            ring[s][0] = f0.x; ring[s][1] = f0.y; ring[s][2] = f0.z; ring[s][3] = f0.w;
            ring[s][4] = f1.x; ring[s][5] = f1.y; ring[s][6] = f1.z; ring[s][7] = f1.w;
        }

        // x[k] = source row rr, col 8t-5+k, k=0..17
        const float* c = ring[rr % 4];
        float x[18];
#pragma unroll
        for (int k = 0; k < 5; ++k) x[k] = __shfl(c[3 + k], laneL);
#pragma unroll
        for (int k = 0; k < 8; ++k) x[5 + k] = c[k];
#pragma unroll
        for (int k = 0; k < 5; ++k) x[13 + k] = __shfl(c[k], laneR);

        const int r_off = rr - 5;
#pragma unroll
        for (int q = 0; q < 8; ++q) {
            const float p0 = x[5 + q];
            const float p1 = x[4 + q] + x[6 + q];
            const float p2 = x[3 + q] + x[7 + q];
            const float p3 = x[2 + q] + x[8 + q];
            const float p4 = x[1 + q] + x[9 + q];
            const float p5 = x[0 + q] + x[10 + q];
            const float h0 = w1 * p1 + w2 * p2 + w3 * p3 + w4 * p4 + w5 * p5;
            const float h1 = w1 * p0 + w2 * p1 + w3 * p2 + w4 * p3 + w5 * p4;
            const float h2 = w2 * p0 + w3 * p1 + w4 * p2 + w5 * p3;
            const float h3 = w3 * p0 + w4 * p1 + w5 * p2;
            const float h4 = w4 * p0 + w5 * p1;
            const float h5 = w5 * p0;

            // a = 5 upper is the FIRST touch of output row rr -> assignment
            if (r_off + 5 >= 0 && r_off + 5 < LC_TY) acc[(r_off + 5) % 11][q] = h5;
            if (r_off - 5 >= 0 && r_off - 5 < LC_TY) acc[(r_off - 5) % 11][q] += h5;
            if (r_off + 4 >= 0 && r_off + 4 < LC_TY) acc[(r_off + 4) % 11][q] += h4;
            if (r_off - 4 >= 0 && r_off - 4 < LC_TY) acc[(r_off - 4) % 11][q] += h4;
            if (r_off + 3 >= 0 && r_off + 3 < LC_TY) acc[(r_off + 3) % 11][q] += h3;
            if (r_off - 3 >= 0 && r_off - 3 < LC_TY) acc[(r_off - 3) % 11][q] += h3;
            if (r_off + 2 >= 0 && r_off + 2 < LC_TY) acc[(r_off + 2) % 11][q] += h2;
            if (r_off - 2 >= 0 && r_off - 2 < LC_TY) acc[(r_off - 2) % 11][q] += h2;
            if (r_off + 1 >= 0 && r_off + 1 < LC_TY) acc[(r_off + 1) % 11][q] += h1;
            if (r_off - 1 >= 0 && r_off - 1 < LC_TY) acc[(r_off - 1) % 11][q] += h1;
            if (r_off >= 0 && r_off < LC_TY)         acc[r_off % 11][q]       += h0;
        }

        // output row oc = rr - 10 is complete
        const int oc = rr - 10;
        if (oc >= 0 && oc < LC_TY) {
            const int slot = oc % 11;
            float* op = dst + (r0 + oc) * LC_W + t * 8;
            float4 f0, f1;
            f0.x = acc[slot][0]; f0.y = acc[slot][1]; f0.z = acc[slot][2]; f0.w = acc[slot][3];
            f1.x = acc[slot][4]; f1.y = acc[slot][5]; f1.z = acc[slot][6]; f1.w = acc[slot][7];
            *reinterpret_cast<float4*>(op) = f0;
            *reinterpret_cast<float4*>(op + 4) = f1;
        }
    }
}

extern "C" void kernel_launch(void* const* d_in, const int* in_sizes, int n_in,
                              void* d_out, int out_size, void* d_ws, size_t ws_size,
                              hipStream_t stream) {
    const float* grid_spikes = (const float*)d_in[0];       // 64*512*512 fp32
    const float* distance_weights = (const float*)d_in[1];  // 5 fp32
    float* out = (float*)d_out;

    dim3 grid(LC_H / LC_TY, 64);  // 32 strips x 64 batches = 2048 single-wave blocks
    dim3 block(64);
    LocalConnectivity_kernel<<<grid, block, 0, stream>>>(grid_spikes, distance_weights, out);
}